// Round 1
// baseline (352.324 us; speedup 1.0000x reference)
//
#include <hip/hip_runtime.h>
#include <hip/hip_bf16.h>
#include <stdint.h>

typedef unsigned short u16;
typedef __attribute__((ext_vector_type(8))) short short8;
typedef __attribute__((ext_vector_type(4))) float floatx4;

#define DEV static __device__ __forceinline__

DEV u16 f2bf(float f) {
  __hip_bfloat16 h = __float2bfloat16(f);
  return __builtin_bit_cast(u16, h);
}

DEV floatx4 mfma16(short8 a, short8 b, floatx4 c) {
  return __builtin_amdgcn_mfma_f32_16x16x32_bf16(a, b, c, 0, 0, 0);
}

DEV void gload_lds16(const void* g, void* l) {
  __builtin_amdgcn_global_load_lds(
      (void __attribute__((address_space(1)))*)(g),
      (void __attribute__((address_space(3)))*)(l),
      16, 0, 0);
}

// ---------------------------------------------------------------- cast f32->bf16
__global__ void cast_kernel(const float* __restrict__ in, u16* __restrict__ out, int n4) {
  int i = blockIdx.x * 256 + threadIdx.x;
  if (i >= n4) return;
  float4 v = reinterpret_cast<const float4*>(in)[i];
  ushort4 o;
  o.x = f2bf(v.x); o.y = f2bf(v.y); o.z = f2bf(v.z); o.w = f2bf(v.w);
  reinterpret_cast<ushort4*>(out)[i] = o;
}

// ---------------------------------------------------------------- GEMM  C[M,N] = A[M,K] * W[N,K]^T
// MODE 0: QKV projection epilogue -> scatter to Q/K/V [B,H,S,dh] bf16, Q scaled by 0.125
// MODE 1: plain f32 output C[M,N]
template <int MODE>
__global__ __launch_bounds__(256, 2)
void gemm_bt(const u16* __restrict__ A, const u16* __restrict__ W,
             int M, int N, int K,
             u16* __restrict__ Qb, u16* __restrict__ Kb, u16* __restrict__ Vb,
             float* __restrict__ C) {
  __shared__ u16 As[128 * 32];
  __shared__ u16 Bs[128 * 32];
  const int tid = threadIdx.x;
  const int wave = tid >> 6, lane = tid & 63;
  const int lr = lane & 15, lg = lane >> 4;
  const int m0 = blockIdx.y * 128, n0 = blockIdx.x * 128;
  const int mq0 = (wave >> 1) * 64, nq0 = (wave & 1) * 64;
  const int srow = lane >> 2;        // row within 16-row segment
  const int sk8  = (lane & 3) * 8;   // k offset (elements)

  floatx4 acc[4][4];
#pragma unroll
  for (int i = 0; i < 4; ++i)
#pragma unroll
    for (int j = 0; j < 4; ++j) acc[i][j] = (floatx4)0.f;

  for (int kt = 0; kt < K; kt += 32) {
    __syncthreads();  // previous tile's compute done -> LDS free
#pragma unroll
    for (int i = 0; i < 2; ++i) {
      int seg = wave + 4 * i;                     // 0..7 -> 16 rows each
      int r = seg * 16 + srow;
      gload_lds16(&A[(size_t)(m0 + r) * K + kt + sk8], &As[seg * 512]);
      gload_lds16(&W[(size_t)(n0 + r) * K + kt + sk8], &Bs[seg * 512]);
    }
    __syncthreads();  // drains vmcnt -> LDS tiles ready

    short8 af[4], bf[4];
#pragma unroll
    for (int t = 0; t < 4; ++t)
      af[t] = *reinterpret_cast<const short8*>(&As[(mq0 + t * 16 + lr) * 32 + lg * 8]);
#pragma unroll
    for (int t = 0; t < 4; ++t)
      bf[t] = *reinterpret_cast<const short8*>(&Bs[(nq0 + t * 16 + lr) * 32 + lg * 8]);
#pragma unroll
    for (int i = 0; i < 4; ++i)
#pragma unroll
      for (int j = 0; j < 4; ++j)
        acc[i][j] = mfma16(af[i], bf[j], acc[i][j]);
  }

  // epilogue: C/D layout col = lane&15, row = (lane>>4)*4 + reg  [m89-verified]
  if (MODE == 0) {
#pragma unroll
    for (int j = 0; j < 4; ++j) {
      int n = n0 + nq0 + j * 16 + lr;     // 0..3071
      int which = n >> 10;                // 0=q 1=k 2=v
      int d = n & 1023;
      int h = d >> 6, dh = d & 63;
      u16* dst = (which == 0) ? Qb : ((which == 1) ? Kb : Vb);
      float scale = (which == 0) ? 0.125f : 1.0f;
#pragma unroll
      for (int i = 0; i < 4; ++i) {
#pragma unroll
        for (int r = 0; r < 4; ++r) {
          int m = m0 + mq0 + i * 16 + lg * 4 + r;
          int b = m >> 11, s = m & 2047;
          dst[((size_t)(b * 16 + h) * 2048 + s) * 64 + dh] = f2bf(acc[i][j][r] * scale);
        }
      }
    }
  } else {
#pragma unroll
    for (int i = 0; i < 4; ++i)
#pragma unroll
      for (int j = 0; j < 4; ++j)
#pragma unroll
        for (int r = 0; r < 4; ++r) {
          int m = m0 + mq0 + i * 16 + lg * 4 + r;
          int n = n0 + nq0 + j * 16 + lr;
          C[(size_t)m * N + n] = acc[i][j][r];
        }
  }
}

// ---------------------------------------------------------------- flash attention (causal)
// grid (16 q-tiles, 64 bh). 4 waves x 32 q-rows. KV tiles of 64.
// Q pre-scaled by 0.125 at QKV epilogue.
__global__ __launch_bounds__(256, 2)
void attn_kernel(const u16* __restrict__ Qb, const u16* __restrict__ Kb,
                 const u16* __restrict__ Vb, u16* __restrict__ Ob) {
  const int qt = blockIdx.x, bh = blockIdx.y;
  const u16* Qh = Qb + (size_t)bh * 2048 * 64;
  const u16* Kh = Kb + (size_t)bh * 2048 * 64;
  const u16* Vh = Vb + (size_t)bh * 2048 * 64;

  __shared__ u16 Ks[64 * 72];      // [kv][d], rows padded to 72 (144B = 9*16)
  __shared__ u16 Vt[64 * 72];      // [d][kv], transposed V tile
  __shared__ u16 Ps[4][32 * 72];   // per-wave P tile [q][kv]

  const int tid = threadIdx.x, wave = tid >> 6, lane = tid & 63;
  const int lr = lane & 15, lg = lane >> 4;
  const int q0 = qt * 128 + wave * 32;

  // Q fragments in registers (A-operand): row = lane&15, k = (lane>>4)*8..+8
  short8 qf[2][2];
#pragma unroll
  for (int mq = 0; mq < 2; ++mq)
#pragma unroll
    for (int kd = 0; kd < 2; ++kd)
      qf[mq][kd] = *reinterpret_cast<const short8*>(
          &Qh[(size_t)(q0 + mq * 16 + lr) * 64 + kd * 32 + lg * 8]);

  floatx4 acc_o[2][4];
#pragma unroll
  for (int i = 0; i < 2; ++i)
#pragma unroll
    for (int j = 0; j < 4; ++j) acc_o[i][j] = (floatx4)0.f;
  float m_run[2][4], l_run[2][4];
#pragma unroll
  for (int i = 0; i < 2; ++i)
#pragma unroll
    for (int r = 0; r < 4; ++r) { m_run[i][r] = -1e30f; l_run[i][r] = 0.f; }

  const int ktiles = (qt + 1) * 2;
  for (int t = 0; t < ktiles; ++t) {
    const int kv0 = t * 64;
    __syncthreads();
    // stage K [64][64] -> Ks, and V transposed -> Vt
#pragma unroll
    for (int i = 0; i < 2; ++i) {
      int g = tid + i * 256;            // 0..511
      int r = g >> 3, c8 = (g & 7) * 8;
      short8 kv_ = *reinterpret_cast<const short8*>(&Kh[(size_t)(kv0 + r) * 64 + c8]);
      *reinterpret_cast<short8*>(&Ks[r * 72 + c8]) = kv_;
      short8 vv = *reinterpret_cast<const short8*>(&Vh[(size_t)(kv0 + r) * 64 + c8]);
#pragma unroll
      for (int j = 0; j < 8; ++j) Vt[(c8 + j) * 72 + r] = (u16)vv[j];
    }
    __syncthreads();

    // QK^T : s[q 2x16][kv 4x16]
    floatx4 s[2][4];
#pragma unroll
    for (int i = 0; i < 2; ++i)
#pragma unroll
      for (int j = 0; j < 4; ++j) s[i][j] = (floatx4)0.f;
#pragma unroll
    for (int kd = 0; kd < 2; ++kd) {
#pragma unroll
      for (int kq = 0; kq < 4; ++kq) {
        short8 kf = *reinterpret_cast<const short8*>(&Ks[(kq * 16 + lr) * 72 + kd * 32 + lg * 8]);
#pragma unroll
        for (int mq = 0; mq < 2; ++mq) s[mq][kq] = mfma16(qf[mq][kd], kf, s[mq][kq]);
      }
    }
    // causal mask (only tiles near diagonal)
    if (kv0 + 63 > q0) {
#pragma unroll
      for (int mq = 0; mq < 2; ++mq)
#pragma unroll
        for (int kq = 0; kq < 4; ++kq)
#pragma unroll
          for (int r = 0; r < 4; ++r) {
            int q = q0 + mq * 16 + lg * 4 + r;
            int kv = kv0 + kq * 16 + lr;
            if (kv > q) s[mq][kq][r] = -1e30f;
          }
    }
    // online softmax; row stats live in lanes of matching C/D row
#pragma unroll
    for (int mq = 0; mq < 2; ++mq) {
#pragma unroll
      for (int r = 0; r < 4; ++r) {
        float v = fmaxf(fmaxf(s[mq][0][r], s[mq][1][r]), fmaxf(s[mq][2][r], s[mq][3][r]));
#pragma unroll
        for (int off = 1; off < 16; off <<= 1) v = fmaxf(v, __shfl_xor(v, off));
        float mn = fmaxf(m_run[mq][r], v);
        float fac = __expf(m_run[mq][r] - mn);
        m_run[mq][r] = mn;
        float rs = 0.f;
#pragma unroll
        for (int kq = 0; kq < 4; ++kq) {
          float p = __expf(s[mq][kq][r] - mn);
          s[mq][kq][r] = p;
          rs += p;
        }
#pragma unroll
        for (int off = 1; off < 16; off <<= 1) rs += __shfl_xor(rs, off);
        l_run[mq][r] = l_run[mq][r] * fac + rs;
#pragma unroll
        for (int nd = 0; nd < 4; ++nd) acc_o[mq][nd][r] *= fac;
      }
    }
    // P -> per-wave LDS (re-layout for A-operand)
#pragma unroll
    for (int mq = 0; mq < 2; ++mq)
#pragma unroll
      for (int kq = 0; kq < 4; ++kq)
#pragma unroll
        for (int r = 0; r < 4; ++r)
          Ps[wave][(mq * 16 + lg * 4 + r) * 72 + kq * 16 + lr] = f2bf(s[mq][kq][r]);
    // PV
#pragma unroll
    for (int ks = 0; ks < 2; ++ks) {
      short8 vf[4];
#pragma unroll
      for (int nd = 0; nd < 4; ++nd)
        vf[nd] = *reinterpret_cast<const short8*>(&Vt[(nd * 16 + lr) * 72 + ks * 32 + lg * 8]);
#pragma unroll
      for (int mq = 0; mq < 2; ++mq) {
        short8 pf = *reinterpret_cast<const short8*>(&Ps[wave][(mq * 16 + lr) * 72 + ks * 32 + lg * 8]);
#pragma unroll
        for (int nd = 0; nd < 4; ++nd) acc_o[mq][nd] = mfma16(pf, vf[nd], acc_o[mq][nd]);
      }
    }
  }

  // epilogue -> attn_out [B,S,D] bf16, d = h*64 + dh
  const int b = bh >> 4, h = bh & 15;
#pragma unroll
  for (int mq = 0; mq < 2; ++mq)
#pragma unroll
    for (int r = 0; r < 4; ++r) {
      int q = q0 + mq * 16 + lg * 4 + r;
      float inv = 1.0f / l_run[mq][r];
#pragma unroll
      for (int nd = 0; nd < 4; ++nd)
        Ob[((size_t)(b * 2048 + q)) * 1024 + h * 64 + nd * 16 + lr] =
            f2bf(acc_o[mq][nd][r] * inv);
    }
}

// ---------------------------------------------------------------- launch
extern "C" void kernel_launch(void* const* d_in, const int* in_sizes, int n_in,
                              void* d_out, int out_size, void* d_ws, size_t ws_size,
                              hipStream_t stream) {
  const float* x    = (const float*)d_in[0];   // [4,2048,1024]
  const float* win  = (const float*)d_in[1];   // [3072,1024]
  const float* wout = (const float*)d_in[2];   // [1024,1024]
  float* out = (float*)d_out;                  // [4,2048,1024] f32

  // workspace layout (needs ~92 MB)
  char* ws = (char*)d_ws;
  u16* xb    = (u16*)(ws + 0);          // 16 MB
  u16* winb  = (u16*)(ws + 16777216);   // 6 MB
  u16* woutb = (u16*)(ws + 23068672);   // 2 MB
  u16* Qb    = (u16*)(ws + 25165824);   // 16 MB  [B,H,S,dh] bf16, pre-scaled 0.125
  u16* Kb    = (u16*)(ws + 41943040);   // 16 MB
  u16* Vb    = (u16*)(ws + 58720256);   // 16 MB
  u16* Ob    = (u16*)(ws + 75497472);   // 16 MB  attn out [B,S,D] bf16

  cast_kernel<<<8192, 256, 0, stream>>>(x, xb, 2097152);
  cast_kernel<<<3072, 256, 0, stream>>>(win, winb, 786432);
  cast_kernel<<<1024, 256, 0, stream>>>(wout, woutb, 262144);

  // QKV projection: [8192,1024] x [3072,1024]^T
  gemm_bt<0><<<dim3(24, 64), 256, 0, stream>>>(xb, winb, 8192, 3072, 1024,
                                               Qb, Kb, Vb, nullptr);
  // attention
  attn_kernel<<<dim3(16, 64), 256, 0, stream>>>(Qb, Kb, Vb, Ob);
  // output projection: [8192,1024] x [1024,1024]^T -> f32
  gemm_bt<1><<<dim3(8, 64), 256, 0, stream>>>(Ob, woutb, 8192, 1024, 1024,
                                              nullptr, nullptr, nullptr, out);
}

// Round 2
// 231.605 us; speedup vs baseline: 1.5212x; 1.5212x over previous
//
#include <hip/hip_runtime.h>
#include <hip/hip_bf16.h>
#include <stdint.h>

typedef unsigned short u16;
typedef __attribute__((ext_vector_type(8))) short short8;
typedef __attribute__((ext_vector_type(4))) float floatx4;

#define DEV static __device__ __forceinline__

DEV u16 f2bf(float f) {
  __hip_bfloat16 h = __float2bfloat16(f);
  return __builtin_bit_cast(u16, h);
}

DEV float fexp2(float x) {  // D = 2^x, single trans op
  float r;
  asm("v_exp_f32 %0, %1" : "=v"(r) : "v"(x));
  return r;
}

DEV floatx4 mfma16(short8 a, short8 b, floatx4 c) {
  return __builtin_amdgcn_mfma_f32_16x16x32_bf16(a, b, c, 0, 0, 0);
}

DEV void gload_lds16(const void* g, void* l) {
  __builtin_amdgcn_global_load_lds(
      (void __attribute__((address_space(1)))*)(g),
      (void __attribute__((address_space(3)))*)(l),
      16, 0, 0);
}

// ---------------------------------------------------------------- cast f32->bf16
__global__ void cast_kernel(const float* __restrict__ in, u16* __restrict__ out, int n4) {
  int i = blockIdx.x * 256 + threadIdx.x;
  if (i >= n4) return;
  float4 v = reinterpret_cast<const float4*>(in)[i];
  ushort4 o;
  o.x = f2bf(v.x); o.y = f2bf(v.y); o.z = f2bf(v.z); o.w = f2bf(v.w);
  reinterpret_cast<ushort4*>(out)[i] = o;
}

// ---------------------------------------------------------------- GEMM  C[M,N] = A[M,K] * W[N,K]^T
// MODE 0: QKV projection epilogue -> scatter to Q/K/V [B,H,S,dh] bf16, Q scaled by 0.125*log2e
// MODE 1: plain f32 output C[M,N]
template <int MODE>
__global__ __launch_bounds__(256, 2)
void gemm_bt(const u16* __restrict__ A, const u16* __restrict__ W,
             int M, int N, int K,
             u16* __restrict__ Qb, u16* __restrict__ Kb, u16* __restrict__ Vb,
             float* __restrict__ C) {
  __shared__ u16 As[128 * 32];
  __shared__ u16 Bs[128 * 32];
  const int tid = threadIdx.x;
  const int wave = tid >> 6, lane = tid & 63;
  const int lr = lane & 15, lg = lane >> 4;
  const int m0 = blockIdx.y * 128, n0 = blockIdx.x * 128;
  const int mq0 = (wave >> 1) * 64, nq0 = (wave & 1) * 64;
  const int srow = lane >> 2;        // row within 16-row segment
  const int sk8  = (lane & 3) * 8;   // k offset (elements)

  floatx4 acc[4][4];
#pragma unroll
  for (int i = 0; i < 4; ++i)
#pragma unroll
    for (int j = 0; j < 4; ++j) acc[i][j] = (floatx4)0.f;

  for (int kt = 0; kt < K; kt += 32) {
    __syncthreads();  // previous tile's compute done -> LDS free
#pragma unroll
    for (int i = 0; i < 2; ++i) {
      int seg = wave + 4 * i;                     // 0..7 -> 16 rows each
      int r = seg * 16 + srow;
      gload_lds16(&A[(size_t)(m0 + r) * K + kt + sk8], &As[seg * 512]);
      gload_lds16(&W[(size_t)(n0 + r) * K + kt + sk8], &Bs[seg * 512]);
    }
    __syncthreads();  // drains vmcnt -> LDS tiles ready

    short8 af[4], bf[4];
#pragma unroll
    for (int t = 0; t < 4; ++t)
      af[t] = *reinterpret_cast<const short8*>(&As[(mq0 + t * 16 + lr) * 32 + lg * 8]);
#pragma unroll
    for (int t = 0; t < 4; ++t)
      bf[t] = *reinterpret_cast<const short8*>(&Bs[(nq0 + t * 16 + lr) * 32 + lg * 8]);
#pragma unroll
    for (int i = 0; i < 4; ++i)
#pragma unroll
      for (int j = 0; j < 4; ++j)
        acc[i][j] = mfma16(af[i], bf[j], acc[i][j]);
  }

  // epilogue: C/D layout col = lane&15, row = (lane>>4)*4 + reg  [m89-verified]
  if (MODE == 0) {
#pragma unroll
    for (int j = 0; j < 4; ++j) {
      int n = n0 + nq0 + j * 16 + lr;     // 0..3071
      int which = n >> 10;                // 0=q 1=k 2=v
      int d = n & 1023;
      int h = d >> 6, dh = d & 63;
      u16* dst = (which == 0) ? Qb : ((which == 1) ? Kb : Vb);
      float scale = (which == 0) ? 0.18033688f : 1.0f;  // 0.125 * log2(e)
#pragma unroll
      for (int i = 0; i < 4; ++i) {
#pragma unroll
        for (int r = 0; r < 4; ++r) {
          int m = m0 + mq0 + i * 16 + lg * 4 + r;
          int b = m >> 11, s = m & 2047;
          dst[((size_t)(b * 16 + h) * 2048 + s) * 64 + dh] = f2bf(acc[i][j][r] * scale);
        }
      }
    }
  } else {
#pragma unroll
    for (int i = 0; i < 4; ++i)
#pragma unroll
      for (int j = 0; j < 4; ++j)
#pragma unroll
        for (int r = 0; r < 4; ++r) {
          int m = m0 + mq0 + i * 16 + lg * 4 + r;
          int n = n0 + nq0 + j * 16 + lr;
          C[(size_t)m * N + n] = acc[i][j][r];
        }
  }
}

// ---------------------------------------------------------------- flash attention (causal)
// Balanced pairing: block x handles q-tiles (x) and (31-x), each 64 rows -> 33 KV-tiles/block.
// 2 waves x 32 q-rows. K staged via pre-swizzled global_load_lds; V reg-transposed into
// XOR-swizzled Vt. Softmax in exp2 domain (Q pre-scaled by 0.125*log2e); defer-max (THR=8).
__global__ __launch_bounds__(128, 2)
void attn_kernel(const u16* __restrict__ Qb, const u16* __restrict__ Kb,
                 const u16* __restrict__ Vb, u16* __restrict__ Ob) {
  const int bh = blockIdx.y;
  const u16* Qh = Qb + (size_t)bh * 2048 * 64;
  const u16* Kh = Kb + (size_t)bh * 2048 * 64;
  const u16* Vh = Vb + (size_t)bh * 2048 * 64;

  __shared__ u16 Ks[64 * 64];      // [kv][d], XOR-swizzled: col^=(row&7)*8 (u16 units)
  __shared__ u16 Vt[64 * 64];      // [d][kv], XOR-swizzled same pattern
  __shared__ u16 Ps[2][32 * 72];   // per-wave P tile [q][kv], padded

  const int tid = threadIdx.x, wave = tid >> 6, lane = tid & 63;
  const int lr = lane & 15, lg = lane >> 4;
  const int swz = (lr & 7) * 8;
  const int b = bh >> 4, h = bh & 15;

  for (int phase = 0; phase < 2; ++phase) {
    const int t64 = phase ? (31 - (int)blockIdx.x) : (int)blockIdx.x;
    const int q0 = t64 * 64 + wave * 32;

    // Q fragments in registers: row = lane&15, k = (lane>>4)*8..+8
    short8 qf[2][2];
#pragma unroll
    for (int mq = 0; mq < 2; ++mq)
#pragma unroll
      for (int kd = 0; kd < 2; ++kd)
        qf[mq][kd] = *reinterpret_cast<const short8*>(
            &Qh[(size_t)(q0 + mq * 16 + lr) * 64 + kd * 32 + lg * 8]);

    floatx4 acc_o[2][4];
#pragma unroll
    for (int i = 0; i < 2; ++i)
#pragma unroll
      for (int j = 0; j < 4; ++j) acc_o[i][j] = (floatx4)0.f;
    float m_run[2][4], l_run[2][4];
#pragma unroll
    for (int i = 0; i < 2; ++i)
#pragma unroll
      for (int r = 0; r < 4; ++r) { m_run[i][r] = -1e30f; l_run[i][r] = 0.f; }

    for (int t = 0; t <= t64; ++t) {
      const int kv0 = t * 64;
      __syncthreads();  // previous tile's LDS reads done
      // stage K via global_load_lds, source pre-swizzled so LDS holds swizzled layout
#pragma unroll
      for (int i = 0; i < 4; ++i) {
        int s = i * 128 + tid;                 // 16B slot id, 512 slots
        int row = s >> 3;
        int col = ((s & 7) ^ (row & 7)) * 8;   // u16 element offset in global row
        gload_lds16(&Kh[(size_t)(kv0 + row) * 64 + col], &Ks[(size_t)s * 8]);
      }
      // stage V transposed: thread loads 2 kv rows x 8 d, writes 8 packed b32
#pragma unroll
      for (int i = 0; i < 2; ++i) {
        int u = i * 128 + tid;
        int p = u & 31, c8 = (u >> 5) * 8;
        short8 v0 = *reinterpret_cast<const short8*>(&Vh[(size_t)(kv0 + 2 * p) * 64 + c8]);
        short8 v1 = *reinterpret_cast<const short8*>(&Vh[(size_t)(kv0 + 2 * p + 1) * 64 + c8]);
#pragma unroll
        for (int j = 0; j < 8; ++j) {
          int d = c8 + j;
          uint32_t pk = (uint32_t)(u16)v0[j] | ((uint32_t)(u16)v1[j] << 16);
          *reinterpret_cast<uint32_t*>(&Vt[d * 64 + ((2 * p) ^ ((d & 7) * 8))]) = pk;
        }
      }
      __syncthreads();  // drains vmcnt+lgkmcnt -> tiles ready

      // QK^T : s4[q 2x16][kv 4x16]  (exp2 domain)
      floatx4 s4[2][4];
#pragma unroll
      for (int i = 0; i < 2; ++i)
#pragma unroll
        for (int j = 0; j < 4; ++j) s4[i][j] = (floatx4)0.f;
#pragma unroll
      for (int kd = 0; kd < 2; ++kd) {
#pragma unroll
        for (int kq = 0; kq < 4; ++kq) {
          short8 kf = *reinterpret_cast<const short8*>(
              &Ks[(kq * 16 + lr) * 64 + ((kd * 32 + lg * 8) ^ swz)]);
#pragma unroll
          for (int mq = 0; mq < 2; ++mq) s4[mq][kq] = mfma16(qf[mq][kd], kf, s4[mq][kq]);
        }
      }
      // causal mask: only the diagonal tile
      if (t == t64) {
#pragma unroll
        for (int mq = 0; mq < 2; ++mq)
#pragma unroll
          for (int kq = 0; kq < 4; ++kq)
#pragma unroll
            for (int r = 0; r < 4; ++r) {
              int q = q0 + mq * 16 + lg * 4 + r;
              int kv = kv0 + kq * 16 + lr;
              if (kv > q) s4[mq][kq][r] = -1e30f;
            }
      }
      // row max (reduce across 16 lanes of the lg-group)
      float nm[2][4];
      bool small_ = true;
#pragma unroll
      for (int mq = 0; mq < 2; ++mq)
#pragma unroll
        for (int r = 0; r < 4; ++r) {
          float v = fmaxf(fmaxf(s4[mq][0][r], s4[mq][1][r]), fmaxf(s4[mq][2][r], s4[mq][3][r]));
#pragma unroll
          for (int off = 1; off < 16; off <<= 1) v = fmaxf(v, __shfl_xor(v, off));
          nm[mq][r] = v;
          small_ = small_ && (v <= m_run[mq][r] + 8.f);
        }
      // defer-max: skip rescale if whole wave's rows grew < 2^8
      if (!__all(small_)) {
#pragma unroll
        for (int mq = 0; mq < 2; ++mq)
#pragma unroll
          for (int r = 0; r < 4; ++r) {
            float mn = fmaxf(m_run[mq][r], nm[mq][r]);
            float fac = fexp2(m_run[mq][r] - mn);
            m_run[mq][r] = mn;
            l_run[mq][r] *= fac;
#pragma unroll
            for (int nd = 0; nd < 4; ++nd) acc_o[mq][nd][r] *= fac;
          }
      }
      // P = 2^(s-m), row sums
#pragma unroll
      for (int mq = 0; mq < 2; ++mq)
#pragma unroll
        for (int r = 0; r < 4; ++r) {
          float rs = 0.f;
#pragma unroll
          for (int kq = 0; kq < 4; ++kq) {
            float p = fexp2(s4[mq][kq][r] - m_run[mq][r]);
            s4[mq][kq][r] = p;
            rs += p;
          }
#pragma unroll
          for (int off = 1; off < 16; off <<= 1) rs += __shfl_xor(rs, off);
          l_run[mq][r] += rs;
        }
      // P -> per-wave LDS (re-layout for A-operand)
#pragma unroll
      for (int mq = 0; mq < 2; ++mq)
#pragma unroll
        for (int kq = 0; kq < 4; ++kq)
#pragma unroll
          for (int r = 0; r < 4; ++r)
            Ps[wave][(mq * 16 + lg * 4 + r) * 72 + kq * 16 + lr] = f2bf(s4[mq][kq][r]);
      // PV
#pragma unroll
      for (int ks = 0; ks < 2; ++ks) {
        short8 vf[4];
#pragma unroll
        for (int nd = 0; nd < 4; ++nd)
          vf[nd] = *reinterpret_cast<const short8*>(
              &Vt[(nd * 16 + lr) * 64 + ((ks * 32 + lg * 8) ^ swz)]);
#pragma unroll
        for (int mq = 0; mq < 2; ++mq) {
          short8 pf = *reinterpret_cast<const short8*>(
              &Ps[wave][(mq * 16 + lr) * 72 + ks * 32 + lg * 8]);
#pragma unroll
          for (int nd = 0; nd < 4; ++nd) acc_o[mq][nd] = mfma16(pf, vf[nd], acc_o[mq][nd]);
        }
      }
    }

    // epilogue -> attn_out [B,S,D] bf16, d = h*64 + dh
#pragma unroll
    for (int mq = 0; mq < 2; ++mq)
#pragma unroll
      for (int r = 0; r < 4; ++r) {
        int q = q0 + mq * 16 + lg * 4 + r;
        float inv = 1.0f / l_run[mq][r];
#pragma unroll
        for (int nd = 0; nd < 4; ++nd)
          Ob[((size_t)(b * 2048 + q)) * 1024 + h * 64 + nd * 16 + lr] =
              f2bf(acc_o[mq][nd][r] * inv);
      }
  }
}

// ---------------------------------------------------------------- launch
extern "C" void kernel_launch(void* const* d_in, const int* in_sizes, int n_in,
                              void* d_out, int out_size, void* d_ws, size_t ws_size,
                              hipStream_t stream) {
  const float* x    = (const float*)d_in[0];   // [4,2048,1024]
  const float* win  = (const float*)d_in[1];   // [3072,1024]
  const float* wout = (const float*)d_in[2];   // [1024,1024]
  float* out = (float*)d_out;                  // [4,2048,1024] f32

  // workspace layout (needs ~92 MB)
  char* ws = (char*)d_ws;
  u16* xb    = (u16*)(ws + 0);          // 16 MB
  u16* winb  = (u16*)(ws + 16777216);   // 6 MB
  u16* woutb = (u16*)(ws + 23068672);   // 2 MB
  u16* Qb    = (u16*)(ws + 25165824);   // 16 MB  [B,H,S,dh] bf16, pre-scaled 0.125*log2e
  u16* Kb    = (u16*)(ws + 41943040);   // 16 MB
  u16* Vb    = (u16*)(ws + 58720256);   // 16 MB
  u16* Ob    = (u16*)(ws + 75497472);   // 16 MB  attn out [B,S,D] bf16

  cast_kernel<<<8192, 256, 0, stream>>>(x, xb, 2097152);
  cast_kernel<<<3072, 256, 0, stream>>>(win, winb, 786432);
  cast_kernel<<<1024, 256, 0, stream>>>(wout, woutb, 262144);

  // QKV projection: [8192,1024] x [3072,1024]^T
  gemm_bt<0><<<dim3(24, 64), 256, 0, stream>>>(xb, winb, 8192, 3072, 1024,
                                               Qb, Kb, Vb, nullptr);
  // attention (balanced q-tile pairs)
  attn_kernel<<<dim3(16, 64), 128, 0, stream>>>(Qb, Kb, Vb, Ob);
  // output projection: [8192,1024] x [1024,1024]^T -> f32
  gemm_bt<1><<<dim3(8, 64), 256, 0, stream>>>(Ob, woutb, 8192, 1024, 1024,
                                              nullptr, nullptr, nullptr, out);
}

// Round 5
// 184.100 us; speedup vs baseline: 1.9138x; 1.2580x over previous
//
#include <hip/hip_runtime.h>
#include <hip/hip_bf16.h>
#include <stdint.h>

typedef unsigned short u16;
typedef __attribute__((ext_vector_type(8))) short short8;
typedef __attribute__((ext_vector_type(4))) float floatx4;
typedef __attribute__((ext_vector_type(16))) float floatx16;
typedef __attribute__((ext_vector_type(4))) unsigned uint4v;
typedef __attribute__((ext_vector_type(2))) unsigned uint2v;

#define DEV static __device__ __forceinline__

DEV u16 f2bf(float f) {
  __hip_bfloat16 h = __float2bfloat16(f);
  return __builtin_bit_cast(u16, h);
}

DEV float fexp2(float x) {
  float r;
  asm("v_exp_f32 %0, %1" : "=v"(r) : "v"(x));
  return r;
}

DEV unsigned cvtpk(float lo, float hi) {  // packs (lo,hi) -> 2x bf16 in one u32
  unsigned r;
  asm("v_cvt_pk_bf16_f32 %0, %1, %2" : "=v"(r) : "v"(lo), "v"(hi));
  return r;
}

// v_permlane32_swap_b32 via the intrinsic (pure function -> no register-alias UB):
// returns {new_vdst, new_vsrc} = {{a_lo,b_lo}, {a_hi,b_hi}}.
DEV void pswap(unsigned& a, unsigned& b) {
  uint2v r = __builtin_amdgcn_permlane32_swap(a, b, false, false);
  a = r[0];
  b = r[1];
}

// After this, x = (lane<32 ? self : partner), y = (lane<32 ? partner : self).
// fmax(x,y) / (x+y) are symmetric -> cross-half combine valid in ALL lanes
// regardless of which output word is which.
DEV void cross32(float v, float& x, float& y) {
  unsigned a = __builtin_bit_cast(unsigned, v), b = a;
  pswap(a, b);
  x = __builtin_bit_cast(float, a);
  y = __builtin_bit_cast(float, b);
}

DEV floatx4 mfma16(short8 a, short8 b, floatx4 c) {
  return __builtin_amdgcn_mfma_f32_16x16x32_bf16(a, b, c, 0, 0, 0);
}
DEV floatx16 mfma32(short8 a, short8 b, floatx16 c) {
  return __builtin_amdgcn_mfma_f32_32x32x16_bf16(a, b, c, 0, 0, 0);
}

DEV void gload_lds16(const void* g, void* l) {
  __builtin_amdgcn_global_load_lds(
      (void __attribute__((address_space(1)))*)(g),
      (void __attribute__((address_space(3)))*)(l),
      16, 0, 0);
}

// ---------------------------------------------------------------- cast f32->bf16
__global__ void cast_kernel(const float* __restrict__ in, u16* __restrict__ out, int n4) {
  int i = blockIdx.x * 256 + threadIdx.x;
  if (i >= n4) return;
  float4 v = reinterpret_cast<const float4*>(in)[i];
  ushort4 o;
  o.x = f2bf(v.x); o.y = f2bf(v.y); o.z = f2bf(v.z); o.w = f2bf(v.w);
  reinterpret_cast<ushort4*>(out)[i] = o;
}

// ---------------------------------------------------------------- GEMM  C[M,N] = A[M,K] * W[N,K]^T
template <int MODE>
__global__ __launch_bounds__(256, 2)
void gemm_bt(const u16* __restrict__ A, const u16* __restrict__ W,
             int M, int N, int K,
             u16* __restrict__ Qb, u16* __restrict__ Kb, u16* __restrict__ Vb,
             float* __restrict__ C) {
  __shared__ u16 As[128 * 32];
  __shared__ u16 Bs[128 * 32];
  const int tid = threadIdx.x;
  const int wave = tid >> 6, lane = tid & 63;
  const int lr = lane & 15, lg = lane >> 4;
  const int m0 = blockIdx.y * 128, n0 = blockIdx.x * 128;
  const int mq0 = (wave >> 1) * 64, nq0 = (wave & 1) * 64;
  const int srow = lane >> 2;
  const int sk8  = (lane & 3) * 8;

  floatx4 acc[4][4];
#pragma unroll
  for (int i = 0; i < 4; ++i)
#pragma unroll
    for (int j = 0; j < 4; ++j) acc[i][j] = (floatx4)0.f;

  for (int kt = 0; kt < K; kt += 32) {
    __syncthreads();
#pragma unroll
    for (int i = 0; i < 2; ++i) {
      int seg = wave + 4 * i;
      int r = seg * 16 + srow;
      gload_lds16(&A[(size_t)(m0 + r) * K + kt + sk8], &As[seg * 512]);
      gload_lds16(&W[(size_t)(n0 + r) * K + kt + sk8], &Bs[seg * 512]);
    }
    __syncthreads();

    short8 af[4], bf[4];
#pragma unroll
    for (int t = 0; t < 4; ++t)
      af[t] = *reinterpret_cast<const short8*>(&As[(mq0 + t * 16 + lr) * 32 + lg * 8]);
#pragma unroll
    for (int t = 0; t < 4; ++t)
      bf[t] = *reinterpret_cast<const short8*>(&Bs[(nq0 + t * 16 + lr) * 32 + lg * 8]);
#pragma unroll
    for (int i = 0; i < 4; ++i)
#pragma unroll
      for (int j = 0; j < 4; ++j)
        acc[i][j] = mfma16(af[i], bf[j], acc[i][j]);
  }

  if (MODE == 0) {
#pragma unroll
    for (int j = 0; j < 4; ++j) {
      int n = n0 + nq0 + j * 16 + lr;
      int which = n >> 10;
      int d = n & 1023;
      int h = d >> 6, dh = d & 63;
      u16* dst = (which == 0) ? Qb : ((which == 1) ? Kb : Vb);
      float scale = (which == 0) ? 0.18033688f : 1.0f;  // 0.125 * log2(e)
#pragma unroll
      for (int i = 0; i < 4; ++i) {
#pragma unroll
        for (int r = 0; r < 4; ++r) {
          int m = m0 + mq0 + i * 16 + lg * 4 + r;
          int b = m >> 11, s = m & 2047;
          dst[((size_t)(b * 16 + h) * 2048 + s) * 64 + dh] = f2bf(acc[i][j][r] * scale);
        }
      }
    }
  } else {
#pragma unroll
    for (int i = 0; i < 4; ++i)
#pragma unroll
      for (int j = 0; j < 4; ++j)
#pragma unroll
        for (int r = 0; r < 4; ++r) {
          int m = m0 + mq0 + i * 16 + lg * 4 + r;
          int n = n0 + nq0 + j * 16 + lr;
          C[(size_t)m * N + n] = acc[i][j][r];
        }
  }
}

// ---------------------------------------------------------------- flash attention (causal)
// Swapped-operand structure (T12): S^T = mfma32(K, Q); lane owns P row for q=lane&31
// split across the hi=lane>>5 halves; softmax in-register (cross32 combine);
// P->bf16 B-frags via cvt_pk + permlane32_swap; O^T = mfma32(V^T, P^T).
__global__ __launch_bounds__(256, 2)
void attn_kernel(const u16* __restrict__ Qb, const u16* __restrict__ Kb,
                 const u16* __restrict__ Vb, u16* __restrict__ Ob) {
  const int bh = blockIdx.y;
  const u16* Qh = Qb + (size_t)bh * 2048 * 64;
  const u16* Kh = Kb + (size_t)bh * 2048 * 64;
  const u16* Vh = Vb + (size_t)bh * 2048 * 64;

  __shared__ u16 smem[8192];      // Ks = [0,4096): [kv][d^swz]; Vt = [4096,8192): [d][kv^swz]
  u16* Ks = smem;
  u16* Vt = smem + 4096;

  const int tid = threadIdx.x, wave = tid >> 6, lane = tid & 63;
  const int ln31 = lane & 31, hi = lane >> 5;
  const int swz = (lane & 7) * 8;          // row&7 == lane&7 for rows ln31, ln31+32
  const int b = bh >> 4, h = bh & 15;

  const int vp = tid & 31, vc8 = tid >> 5;  // V-stage slot: kv pair 2*vp, d octet vc8*8

  for (int ph = 0; ph < 2; ++ph) {
    const int tq = ph ? (15 - (int)blockIdx.x) : (int)blockIdx.x;
    const int q0w = tq * 128 + wave * 32;
    const int qrow = q0w + ln31;

    // Q fragments (B operand): col=q=lane&31, k = hi*8+j within 16-dh chunk c
    short8 qf[4];
#pragma unroll
    for (int c = 0; c < 4; ++c)
      qf[c] = *reinterpret_cast<const short8*>(
          &Qh[(size_t)qrow * 64 + c * 16 + hi * 8]);

    floatx16 accO0 = (floatx16)0.f, accO1 = (floatx16)0.f;  // O^T[d][q], d halves
    float m_run = -1e30f, l_run = 0.f;

    const int nt = 2 * (tq + 1);
    for (int t = 0; t < nt; ++t) {
      const int kv0 = t * 64;
      __syncthreads();
      // ---- stage K (pre-swizzled global_load_lds): Ks[row][d ^ (row&7)*8]
#pragma unroll
      for (int i = 0; i < 2; ++i) {
        int s = i * 256 + tid;
        int row = s >> 3;
        int col = ((s & 7) ^ (row & 7)) * 8;
        gload_lds16(&Kh[(size_t)(kv0 + row) * 64 + col], &Ks[(size_t)s * 8]);
      }
      // ---- stage V transposed: Vt[d][kv ^ (d&7)*8]
      {
        short8 v0 = *reinterpret_cast<const short8*>(&Vh[(size_t)(kv0 + 2 * vp) * 64 + vc8 * 8]);
        short8 v1 = *reinterpret_cast<const short8*>(&Vh[(size_t)(kv0 + 2 * vp + 1) * 64 + vc8 * 8]);
#pragma unroll
        for (int j = 0; j < 8; ++j) {
          int d = vc8 * 8 + j;
          uint32_t pk = (uint32_t)(u16)v0[j] | ((uint32_t)(u16)v1[j] << 16);
          *reinterpret_cast<uint32_t*>(&Vt[d * 64 + ((2 * vp) ^ ((d & 7) * 8))]) = pk;
        }
      }
      __syncthreads();

      if (kv0 <= q0w + 31) {  // wave-uniform: skip tiles fully above our diagonal
        // ---- S^T = K . Q^T : lane(q=ln31,hi): S0[reg]=P[kv0+rowmap(reg,hi)][q], S1 +32
        floatx16 S0 = (floatx16)0.f, S1 = (floatx16)0.f;
        __builtin_amdgcn_s_setprio(1);
#pragma unroll
        for (int c = 0; c < 4; ++c) {
          short8 kfA = *reinterpret_cast<const short8*>(
              &Ks[ln31 * 64 + ((c * 16 + hi * 8) ^ swz)]);
          short8 kfB = *reinterpret_cast<const short8*>(
              &Ks[(32 + ln31) * 64 + ((c * 16 + hi * 8) ^ swz)]);
          S0 = mfma32(kfA, qf[c], S0);
          S1 = mfma32(kfB, qf[c], S1);
        }
        __builtin_amdgcn_s_setprio(0);
        // ---- causal mask (diagonal tiles only)
        if (kv0 + 63 > q0w) {
#pragma unroll
          for (int reg = 0; reg < 16; ++reg) {
            int kvA = kv0 + (reg & 3) + 8 * (reg >> 2) + 4 * hi;
            if (kvA > qrow) S0[reg] = -1e30f;
            if (kvA + 32 > qrow) S1[reg] = -1e30f;
          }
        }
        // ---- row max: tree over own 32 values + cross-half combine
        float m8[8];
#pragma unroll
        for (int i = 0; i < 8; ++i)
          m8[i] = fmaxf(fmaxf(S0[i], S0[i + 8]), fmaxf(S1[i], S1[i + 8]));
        float mx = fmaxf(fmaxf(fmaxf(m8[0], m8[1]), fmaxf(m8[2], m8[3])),
                         fmaxf(fmaxf(m8[4], m8[5]), fmaxf(m8[6], m8[7])));
        {
          float xa, xb;
          cross32(mx, xa, xb);
          mx = fmaxf(xa, xb);
        }
        // ---- defer-max (THR = 8 in exp2 domain)
        bool small_ = (mx <= m_run + 8.f);
        if (!__all(small_)) {
          float mn = fmaxf(m_run, mx);
          float fac = fexp2(m_run - mn);
          m_run = mn;
          l_run *= fac;
          accO0 *= fac;
          accO1 *= fac;
        }
        // ---- P = 2^(s-m) in place, row sum
#pragma unroll
        for (int i = 0; i < 16; ++i) S0[i] = fexp2(S0[i] - m_run);
#pragma unroll
        for (int i = 0; i < 16; ++i) S1[i] = fexp2(S1[i] - m_run);
        float a8[8];
#pragma unroll
        for (int i = 0; i < 8; ++i)
          a8[i] = (S0[i] + S0[i + 8]) + (S1[i] + S1[i + 8]);
        float rs = ((a8[0] + a8[1]) + (a8[2] + a8[3])) + ((a8[4] + a8[5]) + (a8[6] + a8[7]));
        {
          float xa, xb;
          cross32(rs, xa, xb);
          rs = xa + xb;
        }
        l_run += rs;
        // ---- build P^T B-frags: slot k=hi*8+j needs P[16c+k][q].
        // pswap(u01, u45): u01 -> {u01_lo,u45_lo} = word0; u45 -> {u01_hi,u45_hi} = word2.
        short8 pf[4];
#define BUILD_PF(idx, S, base)                                        \
        {                                                             \
          unsigned u01 = cvtpk(S[base + 0], S[base + 1]);             \
          unsigned u23 = cvtpk(S[base + 2], S[base + 3]);             \
          unsigned u45 = cvtpk(S[base + 4], S[base + 5]);             \
          unsigned u67 = cvtpk(S[base + 6], S[base + 7]);             \
          pswap(u01, u45);                                            \
          pswap(u23, u67);                                            \
          uint4v w; w.x = u01; w.y = u23; w.z = u45; w.w = u67;       \
          pf[idx] = __builtin_bit_cast(short8, w);                    \
        }
        BUILD_PF(0, S0, 0)
        BUILD_PF(1, S0, 8)
        BUILD_PF(2, S1, 0)
        BUILD_PF(3, S1, 8)
#undef BUILD_PF
        // ---- O^T += V^T . P^T
        __builtin_amdgcn_s_setprio(1);
#pragma unroll
        for (int c = 0; c < 4; ++c) {
          short8 vfA = *reinterpret_cast<const short8*>(
              &Vt[ln31 * 64 + ((c * 16 + hi * 8) ^ swz)]);
          short8 vfB = *reinterpret_cast<const short8*>(
              &Vt[(32 + ln31) * 64 + ((c * 16 + hi * 8) ^ swz)]);
          accO0 = mfma32(vfA, pf[c], accO0);
          accO1 = mfma32(vfB, pf[c], accO1);
        }
        __builtin_amdgcn_s_setprio(0);
      }
    }

    // ---- epilogue: O^T -> per-wave LDS transpose -> coalesced bf16 store
    __syncthreads();  // all waves done reading Ks/Vt
    u16* ep = smem + wave * 2048;  // [32 q][64 d], swizzled
    float inv = 1.0f / l_run;
#define EPI_W(ACC, dh2)                                               \
    {                                                                 \
      _Pragma("unroll")                                               \
      for (int rp = 0; rp < 8; ++rp) {                                \
        int reg = rp * 2;                                             \
        unsigned pk = cvtpk(ACC[reg] * inv, ACC[reg + 1] * inv);      \
        int d = dh2 * 32 + (reg & 3) + 8 * (reg >> 2) + 4 * hi;       \
        *reinterpret_cast<uint32_t*>(                                 \
            &ep[ln31 * 64 + (d ^ ((ln31 & 7) * 8))]) = pk;            \
      }                                                               \
    }
    EPI_W(accO0, 0)
    EPI_W(accO1, 1)
#undef EPI_W
#pragma unroll
    for (int g = 0; g < 4; ++g) {
      int d0 = hi * 32 + g * 8;
      short8 o8 = *reinterpret_cast<const short8*>(
          &ep[ln31 * 64 + (d0 ^ ((ln31 & 7) * 8))]);
      *reinterpret_cast<short8*>(
          &Ob[(size_t)(b * 2048 + q0w + ln31) * 1024 + h * 64 + d0]) = o8;
    }
  }
}

// ---------------------------------------------------------------- launch
extern "C" void kernel_launch(void* const* d_in, const int* in_sizes, int n_in,
                              void* d_out, int out_size, void* d_ws, size_t ws_size,
                              hipStream_t stream) {
  const float* x    = (const float*)d_in[0];   // [4,2048,1024]
  const float* win  = (const float*)d_in[1];   // [3072,1024]
  const float* wout = (const float*)d_in[2];   // [1024,1024]
  float* out = (float*)d_out;                  // [4,2048,1024] f32

  char* ws = (char*)d_ws;
  u16* xb    = (u16*)(ws + 0);          // 16 MB
  u16* winb  = (u16*)(ws + 16777216);   // 6 MB
  u16* woutb = (u16*)(ws + 23068672);   // 2 MB
  u16* Qb    = (u16*)(ws + 25165824);   // 16 MB  [B,H,S,dh] bf16, pre-scaled 0.125*log2e
  u16* Kb    = (u16*)(ws + 41943040);   // 16 MB
  u16* Vb    = (u16*)(ws + 58720256);   // 16 MB
  u16* Ob    = (u16*)(ws + 75497472);   // 16 MB  attn out [B,S,D] bf16

  cast_kernel<<<8192, 256, 0, stream>>>(x, xb, 2097152);
  cast_kernel<<<3072, 256, 0, stream>>>(win, winb, 786432);
  cast_kernel<<<1024, 256, 0, stream>>>(wout, woutb, 262144);

  gemm_bt<0><<<dim3(24, 64), 256, 0, stream>>>(xb, winb, 8192, 3072, 1024,
                                               Qb, Kb, Vb, nullptr);
  attn_kernel<<<dim3(8, 64), 256, 0, stream>>>(Qb, Kb, Vb, Ob);
  gemm_bt<1><<<dim3(8, 64), 256, 0, stream>>>(Ob, woutb, 8192, 1024, 1024,
                                              nullptr, nullptr, nullptr, out);
}